// Round 10
// baseline (207.824 us; speedup 1.0000x reference)
//
#include <hip/hip_runtime.h>
#include <math.h>

typedef _Float16 f16x8 __attribute__((ext_vector_type(8)));
typedef float f32x4 __attribute__((ext_vector_type(4)));
typedef float f32x16 __attribute__((ext_vector_type(16)));

// Problem constants
#define NROWS 32768   // 8*4096 input rows
#define KEMB  8192    // codebook entries
// DIM = 64

#define DECAYF 0.99f
#define OMDF   0.01f

// d_out layout (floats), reference return order
#define OUT_Q    0          // quantized, 2097152
#define OUT_LOSS 2097152    // vq_loss, 1
#define OUT_IDX  2097153    // idx (as float), 32768
#define OUT_PERP 2129921    // perplexity, 1
#define OUT_NW   2129922    // new_weight, 524288
#define OUT_NCC  2654210    // new_cc, 8192
#define OUT_NWS  2662402    // new_ws, 524288

// d_ws layout (4-byte units)
#define WS_N      0
#define WS_ENT    1
#define WS_COUNTS 4                    // 8192 floats (argmin atomics; reused as quant partials)
#define WS_EMB    8196                 // 524288 floats (atomic)
#define WS_IDX    532484               // 32768 ints
#define WS_W2H    565252               // 8192 floats (= ||w||^2 / 2)
#define WS_WFRAG  573444               // 524288 f32 units = 2 MB f16 frag image (32x32 B-layout)
#define WS_ZERO_UNITS 532484           // scalars+counts+emb

__device__ __forceinline__ float sq_rn(float v) { return __fmul_rn(v, v); }

// numpy pairwise_sum order for 64 contiguous squared values
__device__ __forceinline__ float npsumsq64(const float* vbuf) {
  float a[8];
#pragma unroll
  for (int j = 0; j < 8; ++j) a[j] = sq_rn(vbuf[j]);
#pragma unroll
  for (int m = 1; m < 8; ++m)
#pragma unroll
    for (int j = 0; j < 8; ++j) a[j] = __fadd_rn(a[j], sq_rn(vbuf[m*8 + j]));
  return __fadd_rn(__fadd_rn(__fadd_rn(a[0],a[1]), __fadd_rn(a[2],a[3])),
                   __fadd_rn(__fadd_rn(a[4],a[5]), __fadd_rn(a[6],a[7])));
}

// split a float into (hi, lo) fp16 pair; hi+lo reproduces x to ~22 bits
__device__ __forceinline__ void split_f16(float x, _Float16& hi, _Float16& lo) {
  hi = (_Float16)x;
  float r = __fsub_rn(x, (float)hi);   // exact (Sterbenz)
  lo = (_Float16)r;
}

// prep: zero scratch (replaces memset node), w2h = 0.5*||w||^2 (numpy order),
// W -> 32x32-B-fragment image.
// Image layout for mfma_f32_32x32x16_f16: B[col=lane&31][k=(lane>>5)*8+j].
// Chunk c in [0,4): hi of dims [c*16,(c+1)*16); c+4: lo of same dims.
// f16 index: ((P*8 + c)*64 + lane)*8 + j, P = code>>5 (panel of 32 codes).
__global__ __launch_bounds__(256) void prep_kernel(const float* __restrict__ wg,
                                                   float* __restrict__ ws) {
  const int tid = blockIdx.x * 256 + threadIdx.x;   // 73728 total
  // grid-stride zero of scalars+counts+emb
  for (int i = tid; i < WS_ZERO_UNITS; i += 73728) ws[i] = 0.0f;
  if (tid < KEMB) {
    const float* src = wg + (size_t)tid * 64;
    float vbuf[64];
#pragma unroll
    for (int f = 0; f < 16; ++f) {
      float4 v = *(const float4*)(src + f*4);
      vbuf[f*4+0]=v.x; vbuf[f*4+1]=v.y; vbuf[f*4+2]=v.z; vbuf[f*4+3]=v.w;
    }
    ws[WS_W2H + tid] = __fmul_rn(0.5f, npsumsq64(vbuf));
  } else {
    const int u = tid - KEMB;            // 65536 granules: code K, dims g*8..+8
    const int K = u >> 3, g = u & 7;
    const int P = K >> 5, col = K & 31;
    const int c = g >> 1, h = g & 1;
    const int lane_t = col + 32*h;
    const float* src = wg + (size_t)K*64 + g*8;
    float4 v0 = *(const float4*)src, v1 = *(const float4*)(src + 4);
    float vv[8] = {v0.x,v0.y,v0.z,v0.w,v1.x,v1.y,v1.z,v1.w};
    f16x8 hi, lo;
#pragma unroll
    for (int j = 0; j < 8; ++j) { _Float16 hh, ll; split_f16(vv[j], hh, ll); hi[j]=hh; lo[j]=ll; }
    _Float16* wf = (_Float16*)(ws + WS_WFRAG);
    *(f16x8*)&wf[((size_t)(P*8 + c)    *64 + lane_t)*8] = hi;
    *(f16x8*)&wf[((size_t)(P*8 + c + 4)*64 + lane_t)*8] = lo;
  }
}

// argmin v10: 32x32x16 MFMA (99.8%-of-peak shape, half the instrs of 16x16).
// 256 blocks x 512 threads (8 waves = rg2 x cg4), 128 rows/block.
// Wave tile: 64 rows x 32 codes = 2 C-tiles x 12 MFMAs (hh,hl,lh x 4 chunks).
// B-frags from global frag image; explicit depth-2 register dbuf;
// launch_bounds(512,2) => 256-VGPR budget (stops r9's reg-starved reschedule).
__global__ __launch_bounds__(512, 2) void argmin_kernel(const float* __restrict__ xg,
                                                        float* __restrict__ out,
                                                        float* __restrict__ ws) {
  __shared__ __align__(16) _Float16 xp[4*8*64*8];   // 32 KB, X frags (negated), A-layout
  __shared__ float md[128*4];
  __shared__ int   mk[128*4];
  __shared__ int   bkL[128];

  const int t    = threadIdx.x;
  const int lane = t & 63, wv = t >> 6;        // 8 waves
  const int col = lane & 31, half = lane >> 5;
  const int rg = wv >> 2, cg = wv & 3;
  const int row0 = blockIdx.x * 128;
  const _Float16* __restrict__ wfrag = (const _Float16*)(ws + WS_WFRAG);
  const float* __restrict__ w2hg = ws + WS_W2H;

  // ---- prologue: convert X tile (NEGATED) into 32x32-A fragment layout ----
  // A[row=lane&31][k=(lane>>5)*8+j]; xp idx ((rp*8 + c)*64 + lane)*8 + j
#pragma unroll
  for (int it = 0; it < 2; ++it) {
    const int u  = t + 512*it;          // < 1024 granules: row r, dims g*8..+8
    const int r = u >> 3, g = u & 7;
    const int rp = r >> 5, c = g >> 1, h = g & 1;
    const int lane_t = (r & 31) + 32*h;
    const float* src = xg + (size_t)(row0 + r)*64 + g*8;
    float4 v0 = *(const float4*)src, v1 = *(const float4*)(src + 4);
    float vv[8] = {v0.x,v0.y,v0.z,v0.w,v1.x,v1.y,v1.z,v1.w};
    f16x8 hi, lo;
#pragma unroll
    for (int j = 0; j < 8; ++j) { _Float16 hh, ll; split_f16(-vv[j], hh, ll); hi[j]=hh; lo[j]=ll; }
    *(f16x8*)&xp[(((rp*8) + c)    *64 + lane_t)*8] = hi;
    *(f16x8*)&xp[(((rp*8) + c + 4)*64 + lane_t)*8] = lo;
  }
  __syncthreads();

  // A-frags resident: wave's 64 rows = row-panels rg*2, rg*2+1; 8 chunks each
  f16x8 a[2][8];
#pragma unroll
  for (int rt = 0; rt < 2; ++rt)
#pragma unroll
    for (int c = 0; c < 8; ++c)
      a[rt][c] = *(const f16x8*)&xp[(((rg*2+rt)*8 + c)*64 + lane)*8];

  float best[32]; int bestk[32];
#pragma unroll
  for (int i = 0; i < 32; ++i) { best[i] = INFINITY; bestk[i] = 0; }

  const size_t lane8 = (size_t)lane * 8;

#define LOADB32(P, B, CW)                                                    \
  {                                                                          \
    const size_t base = (size_t)(P)*4096 + lane8;                            \
    _Pragma("unroll")                                                        \
    for (int c = 0; c < 8; ++c) B[c] = *(const f16x8*)&wfrag[base + c*512];  \
    CW = w2hg[(P)*32 + col];                                                 \
  }

  // 12 MFMAs/tile: hh (aC,bC) c=0..3; hl (aC,bC+4); lh (aC+4,bC). rt-interleaved.
#define COMPUTE32(P, B, W2)                                                  \
  {                                                                          \
    f32x16 cin;                                                              \
    _Pragma("unroll")                                                        \
    for (int i = 0; i < 16; ++i) cin[i] = (W2);                              \
    f32x16 ac0, ac1;                                                         \
    ac0 = __builtin_amdgcn_mfma_f32_32x32x16_f16(a[0][0], B[0], cin, 0,0,0); \
    ac1 = __builtin_amdgcn_mfma_f32_32x32x16_f16(a[1][0], B[0], cin, 0,0,0); \
    ac0 = __builtin_amdgcn_mfma_f32_32x32x16_f16(a[0][1], B[1], ac0, 0,0,0); \
    ac1 = __builtin_amdgcn_mfma_f32_32x32x16_f16(a[1][1], B[1], ac1, 0,0,0); \
    ac0 = __builtin_amdgcn_mfma_f32_32x32x16_f16(a[0][2], B[2], ac0, 0,0,0); \
    ac1 = __builtin_amdgcn_mfma_f32_32x32x16_f16(a[1][2], B[2], ac1, 0,0,0); \
    ac0 = __builtin_amdgcn_mfma_f32_32x32x16_f16(a[0][3], B[3], ac0, 0,0,0); \
    ac1 = __builtin_amdgcn_mfma_f32_32x32x16_f16(a[1][3], B[3], ac1, 0,0,0); \
    ac0 = __builtin_amdgcn_mfma_f32_32x32x16_f16(a[0][0], B[4], ac0, 0,0,0); \
    ac1 = __builtin_amdgcn_mfma_f32_32x32x16_f16(a[1][0], B[4], ac1, 0,0,0); \
    ac0 = __builtin_amdgcn_mfma_f32_32x32x16_f16(a[0][1], B[5], ac0, 0,0,0); \
    ac1 = __builtin_amdgcn_mfma_f32_32x32x16_f16(a[1][1], B[5], ac1, 0,0,0); \
    ac0 = __builtin_amdgcn_mfma_f32_32x32x16_f16(a[0][2], B[6], ac0, 0,0,0); \
    ac1 = __builtin_amdgcn_mfma_f32_32x32x16_f16(a[1][2], B[6], ac1, 0,0,0); \
    ac0 = __builtin_amdgcn_mfma_f32_32x32x16_f16(a[0][3], B[7], ac0, 0,0,0); \
    ac1 = __builtin_amdgcn_mfma_f32_32x32x16_f16(a[1][3], B[7], ac1, 0,0,0); \
    ac0 = __builtin_amdgcn_mfma_f32_32x32x16_f16(a[0][4], B[0], ac0, 0,0,0); \
    ac1 = __builtin_amdgcn_mfma_f32_32x32x16_f16(a[1][4], B[0], ac1, 0,0,0); \
    ac0 = __builtin_amdgcn_mfma_f32_32x32x16_f16(a[0][5], B[1], ac0, 0,0,0); \
    ac1 = __builtin_amdgcn_mfma_f32_32x32x16_f16(a[1][5], B[1], ac1, 0,0,0); \
    ac0 = __builtin_amdgcn_mfma_f32_32x32x16_f16(a[0][6], B[2], ac0, 0,0,0); \
    ac1 = __builtin_amdgcn_mfma_f32_32x32x16_f16(a[1][6], B[2], ac1, 0,0,0); \
    ac0 = __builtin_amdgcn_mfma_f32_32x32x16_f16(a[0][7], B[3], ac0, 0,0,0); \
    ac1 = __builtin_amdgcn_mfma_f32_32x32x16_f16(a[1][7], B[3], ac1, 0,0,0); \
    const int kk = (P)*32 + col;                                             \
    _Pragma("unroll")                                                        \
    for (int reg = 0; reg < 16; ++reg) {                                     \
      const float d0 = ac0[reg];                                             \
      if (d0 < best[reg])      { best[reg] = d0;      bestk[reg] = kk; }     \
      const float d1 = ac1[reg];                                             \
      if (d1 < best[16+reg])   { best[16+reg] = d1;   bestk[16+reg] = kk; }  \
    }                                                                        \
  }

  f16x8 bp[8], bq[8];
  float pw, qw;
  LOADB32(cg, bp, pw);   // panel index p = it*4 + cg; it=0

  for (int it = 0; it < 64; it += 2) {
    LOADB32((it+1)*4 + cg, bq, qw);
    COMPUTE32(it*4 + cg, bp, pw);
    if (it + 2 < 64) LOADB32((it+2)*4 + cg, bp, pw);
    COMPUTE32((it+1)*4 + cg, bq, qw);
  }

  // ---- merge the 32 code-lanes (col dim) per row (lexicographic (d,k)) ----
#pragma unroll
  for (int bi = 0; bi < 32; ++bi) {
    float bd = best[bi]; int bk = bestk[bi];
#pragma unroll
    for (int m = 1; m < 32; m <<= 1) {     // stays within each 32-lane half
      const float od = __shfl_xor(bd, m, 64);
      const int   ok = __shfl_xor(bk, m, 64);
      if (od < bd || (od == bd && ok < bk)) { bd = od; bk = ok; }
    }
    best[bi] = bd; bestk[bi] = bk;
  }
  if (col == 0) {   // lanes 0 and 32 hold per-row winners for their half
#pragma unroll
    for (int rt = 0; rt < 2; ++rt)
#pragma unroll
      for (int reg = 0; reg < 16; ++reg) {
        const int row = rg*64 + rt*32 + (reg & 3) + 8*(reg >> 2) + 4*half;
        md[row*4 + cg] = best[rt*16 + reg];
        mk[row*4 + cg] = bestk[rt*16 + reg];
      }
  }
  __syncthreads();

  if (t < 128) {
    const int row = t;
    float bd = md[row*4]; int bk = mk[row*4];
#pragma unroll
    for (int u = 1; u < 4; ++u) {
      const float d2 = md[row*4 + u]; const int k2 = mk[row*4 + u];
      if (d2 < bd || (d2 == bd && k2 < bk)) { bd = d2; bk = k2; }
    }
    out[OUT_IDX + row0 + row] = (float)bk;
    ((int*)ws)[WS_IDX + row0 + row] = bk;
    bkL[row] = bk;
    atomicAdd(&ws[WS_COUNTS + bk], 1.0f);
  }
  __syncthreads();

  // ---- fused EMA segment-sum: 8 waves x 16 rows, lane = dim ----
#pragma unroll 4
  for (int r = 0; r < 16; ++r) {
    const int row = wv*16 + r;
    const int k = bkL[row];
    atomicAdd(&ws[WS_EMB + (size_t)k*64 + lane],
              xg[(size_t)(row0 + row)*64 + lane]);
  }
}

// stats: ONE block (1024 threads), no atomics
__global__ __launch_bounds__(1024) void stats_kernel(const float* __restrict__ cc,
                                                     float* __restrict__ out,
                                                     float* __restrict__ ws) {
  const int t = threadIdx.x;
  float v1 = 0.0f, v2 = 0.0f;
#pragma unroll
  for (int i = 0; i < 8; ++i) {
    const int k = i*1024 + t;
    const float cnt = ws[WS_COUNTS + k];
    const float ncc = __fadd_rn(__fmul_rn(DECAYF, cc[k]), __fmul_rn(OMDF, cnt));
    out[OUT_NCC + k] = ncc;
    const float p = cnt * (1.0f/32768.0f);
    v1 += ncc;
    v2 += __fmul_rn(p, logf(__fadd_rn(p, 1e-10f)));
  }
#pragma unroll
  for (int off = 32; off > 0; off >>= 1) {
    v1 += __shfl_down(v1, off);
    v2 += __shfl_down(v2, off);
  }
  __shared__ float s1[16], s2[16];
  const int lane = t & 63, wid = t >> 6;
  if (lane == 0) { s1[wid] = v1; s2[wid] = v2; }
  __syncthreads();
  if (t == 0) {
    float n = 0.0f, e = 0.0f;
#pragma unroll
    for (int i = 0; i < 16; ++i) { n += s1[i]; e += s2[i]; }
    ws[WS_N] = n; ws[WS_ENT] = e;
  }
}

// update: float4-vectorized; 512 blocks x 256 threads
__global__ __launch_bounds__(256) void update_kernel(const float* __restrict__ ws0,
                                                     float* __restrict__ out,
                                                     float* __restrict__ ws) {
  const int e4 = blockIdx.x * 256 + threadIdx.x;  // < 131072 float4s
  const int k = e4 >> 4;
  const float n = ws[WS_N];
  const float ncc = out[OUT_NCC + k];
  const float smoothed = __fmul_rn(__fadd_rn(ncc, 1e-5f) / __fadd_rn(n, 0.08192f), n);
  float4 w0 = *(const float4*)(ws0 + (size_t)e4*4);
  float4 em = *(const float4*)(ws + WS_EMB + (size_t)e4*4);
  float wv[4] = {w0.x, w0.y, w0.z, w0.w};
  float ev[4] = {em.x, em.y, em.z, em.w};
  float nwsv[4], nwv[4];
#pragma unroll
  for (int i = 0; i < 4; ++i) {
    nwsv[i] = __fadd_rn(__fmul_rn(DECAYF, wv[i]), __fmul_rn(OMDF, ev[i]));
    nwv[i]  = nwsv[i] / smoothed;   // exact division (reference: nws / smoothed)
  }
  float4 onws = {nwsv[0], nwsv[1], nwsv[2], nwsv[3]};
  float4 onw  = {nwv[0],  nwv[1],  nwv[2],  nwv[3]};
  *(float4*)(out + OUT_NWS + (size_t)e4*4) = onws;
  *(float4*)(out + OUT_NW  + (size_t)e4*4) = onw;
  if (e4 == 0) out[OUT_PERP] = expf(-ws[WS_ENT]);
}

// quant: per-block partials to distinct slots (WS_COUNTS reused post-stats)
__global__ __launch_bounds__(256) void quant_kernel(const float* __restrict__ xg,
                                                    float* __restrict__ out,
                                                    float* __restrict__ ws) {
  const int t = threadIdx.x;
  const int* idxb = (const int*)ws + WS_IDX;
  float v = 0.0f;
#pragma unroll
  for (int j = 0; j < 4; ++j) {
    const int e4 = (j*512 + blockIdx.x)*256 + t;   // float4 index, coalesced
    const int row = e4 >> 4, d = (e4 & 15) * 4;
    const int k = idxb[row];
    const float* nw = out + OUT_NW + (size_t)k*64 + d;
    float2 q0 = *(const float2*)nw, q1 = *(const float2*)(nw + 2);
    float4 x = *(const float4*)(xg + (size_t)e4*4);
    float qv[4] = {q0.x, q0.y, q1.x, q1.y};
    float xv[4] = {x.x, x.y, x.z, x.w};
    float4 o;
    float ov[4];
#pragma unroll
    for (int i = 0; i < 4; ++i) {
      const float df = __fsub_rn(qv[i], xv[i]);
      ov[i] = __fadd_rn(xv[i], df);
      v = fmaf(df, df, v);
    }
    o.x = ov[0]; o.y = ov[1]; o.z = ov[2]; o.w = ov[3];
    *(float4*)(out + OUT_Q + (size_t)e4*4) = o;
  }
#pragma unroll
  for (int off = 32; off > 0; off >>= 1) v += __shfl_down(v, off);
  __shared__ float sm[4];
  const int lane = t & 63, wid = t >> 6;
  if (lane == 0) sm[wid] = v;
  __syncthreads();
  if (t == 0) ws[WS_COUNTS + blockIdx.x] = (sm[0]+sm[1]) + (sm[2]+sm[3]);
}

__global__ void final_kernel(float* __restrict__ out, const float* __restrict__ ws) {
  const int t = threadIdx.x;   // 64 threads
  float v = 0.0f;
#pragma unroll
  for (int i = 0; i < 8; ++i) v += ws[WS_COUNTS + i*64 + t];
#pragma unroll
  for (int off = 32; off > 0; off >>= 1) v += __shfl_down(v, off);
  if (t == 0) out[OUT_LOSS] = __fmul_rn(0.25f, v / 2097152.0f);
}

extern "C" void kernel_launch(void* const* d_in, const int* in_sizes, int n_in,
                              void* d_out, int out_size, void* d_ws, size_t ws_size,
                              hipStream_t stream) {
  (void)in_sizes; (void)n_in; (void)out_size; (void)ws_size;
  const float* x   = (const float*)d_in[0];
  const float* w   = (const float*)d_in[1];
  const float* cc  = (const float*)d_in[2];
  const float* ws0 = (const float*)d_in[3];
  float* out = (float*)d_out;
  float* ws  = (float*)d_ws;

  hipLaunchKernelGGL(prep_kernel,   dim3(288),  dim3(256),  0, stream, w, ws);
  hipLaunchKernelGGL(argmin_kernel, dim3(256),  dim3(512),  0, stream, x, out, ws);
  hipLaunchKernelGGL(stats_kernel,  dim3(1),    dim3(1024), 0, stream, cc, out, ws);
  hipLaunchKernelGGL(update_kernel, dim3(512),  dim3(256),  0, stream, ws0, out, ws);
  hipLaunchKernelGGL(quant_kernel,  dim3(512),  dim3(256),  0, stream, x, out, ws);
  hipLaunchKernelGGL(final_kernel,  dim3(1),    dim3(64),   0, stream, out, ws);
}

// Round 11
// 189.928 us; speedup vs baseline: 1.0942x; 1.0942x over previous
//
#include <hip/hip_runtime.h>
#include <math.h>

typedef _Float16 f16x8 __attribute__((ext_vector_type(8)));
typedef float f32x4 __attribute__((ext_vector_type(4)));

// Problem constants
#define NROWS 32768   // 8*4096 input rows
#define KEMB  8192    // codebook entries
// DIM = 64

#define DECAYF 0.99f
#define OMDF   0.01f

// d_out layout (floats), reference return order
#define OUT_Q    0          // quantized, 2097152
#define OUT_LOSS 2097152    // vq_loss, 1
#define OUT_IDX  2097153    // idx (as float), 32768
#define OUT_PERP 2129921    // perplexity, 1
#define OUT_NW   2129922    // new_weight, 524288
#define OUT_NCC  2654210    // new_cc, 8192
#define OUT_NWS  2662402    // new_ws, 524288

// d_ws layout (4-byte units)
#define WS_N      0
#define WS_ENT    1
#define WS_COUNTS 4                    // 8192 floats (argmin atomics; read by update & final)
#define WS_EMB    8196                 // 524288 floats (atomic)
#define WS_IDX    532484               // 32768 ints
#define WS_W2H    565252               // 8192 floats (argmin ||w||^2/2; reused: +1024.. = quant loss partials)
#define WS_WFRAG  573444               // 524288 f32 units = 2 MB f16 frag image
#define WS_ZERO_UNITS 532484           // scalars+counts+emb
#define WS_LOSSP  (WS_W2H + 1024)      // 512 quant partials (W2H free after argmin)

__device__ __forceinline__ float sq_rn(float v) { return __fmul_rn(v, v); }

// numpy pairwise_sum order for 64 contiguous squared values
__device__ __forceinline__ float npsumsq64(const float* vbuf) {
  float a[8];
#pragma unroll
  for (int j = 0; j < 8; ++j) a[j] = sq_rn(vbuf[j]);
#pragma unroll
  for (int m = 1; m < 8; ++m)
#pragma unroll
    for (int j = 0; j < 8; ++j) a[j] = __fadd_rn(a[j], sq_rn(vbuf[m*8 + j]));
  return __fadd_rn(__fadd_rn(__fadd_rn(a[0],a[1]), __fadd_rn(a[2],a[3])),
                   __fadd_rn(__fadd_rn(a[4],a[5]), __fadd_rn(a[6],a[7])));
}

// split a float into (hi, lo) fp16 pair; hi+lo reproduces x to ~22 bits
__device__ __forceinline__ void split_f16(float x, _Float16& hi, _Float16& lo) {
  hi = (_Float16)x;
  float r = __fsub_rn(x, (float)hi);   // exact (Sterbenz)
  lo = (_Float16)r;
}

// prep: zero scratch, w2h = 0.5*||w||^2 (numpy order), W -> 16x16 frag image,
// and N = 0.99*sum(cc) + 0.01*32768 (sum(counts)==32768 exactly; ~1e-7 vs ref).
__global__ __launch_bounds__(256) void prep_kernel(const float* __restrict__ wg,
                                                   const float* __restrict__ cc,
                                                   float* __restrict__ ws) {
  const int tid = blockIdx.x * 256 + threadIdx.x;   // 73728 total
  for (int i = tid; i < WS_ZERO_UNITS; i += 73728) ws[i] = 0.0f;
  if (tid < KEMB) {
    const float* src = wg + (size_t)tid * 64;
    float vbuf[64];
#pragma unroll
    for (int f = 0; f < 16; ++f) {
      float4 v = *(const float4*)(src + f*4);
      vbuf[f*4+0]=v.x; vbuf[f*4+1]=v.y; vbuf[f*4+2]=v.z; vbuf[f*4+3]=v.w;
    }
    ws[WS_W2H + tid] = __fmul_rn(0.5f, npsumsq64(vbuf));
  } else if (tid < KEMB + 65536) {
    const int u = tid - KEMB;            // granule: code K, dims g*8..g*8+7
    const int K = u >> 3, g = u & 7;
    const int n = K & 15, P = K >> 4;    // global panel 0..511
    const int slot = (g&3)*16 + n, shi = g >> 2;
    const float* src = wg + (size_t)K*64 + g*8;
    float4 v0 = *(const float4*)src, v1 = *(const float4*)(src + 4);
    float vv[8] = {v0.x,v0.y,v0.z,v0.w,v1.x,v1.y,v1.z,v1.w};
    f16x8 hi, lo;
#pragma unroll
    for (int j = 0; j < 8; ++j) { _Float16 h, l; split_f16(vv[j], h, l); hi[j]=h; lo[j]=l; }
    _Float16* wf = (_Float16*)(ws + WS_WFRAG);
    *(f16x8*)&wf[((size_t)(P*4 + shi)*64 + slot)*8]     = hi;
    *(f16x8*)&wf[((size_t)(P*4 + 2 + shi)*64 + slot)*8] = lo;
  }
  // block 0: N scalar (runs concurrently with other blocks' frag work)
  if (blockIdx.x == 0) {
    float s = 0.0f;
    for (int i = threadIdx.x; i < KEMB; i += 256) s += cc[i];
#pragma unroll
    for (int off = 32; off > 0; off >>= 1) s += __shfl_down(s, off);
    __shared__ float sw[4];
    const int lane = threadIdx.x & 63, wid = threadIdx.x >> 6;
    if (lane == 0) sw[wid] = s;
    __syncthreads();
    if (threadIdx.x == 0)
      ws[WS_N] = __fadd_rn(__fmul_rn(DECAYF, (sw[0]+sw[1])+(sw[2]+sw[3])), 327.68f);
  }
}

// one 16-code panel: 6 MFMA groups (lo_x*lo_w dropped; verified flip-free)
#define COMPUTE_PANEL(I, B0, B1, B2, B3, W2)                                        \
  {                                                                                 \
    const f32x4 cin = {(W2), (W2), (W2), (W2)};                                     \
    f32x4 acc[4];                                                                   \
    _Pragma("unroll")                                                               \
    for (int rt = 0; rt < 4; ++rt) acc[rt] = __builtin_amdgcn_mfma_f32_16x16x32_f16(a[rt][0], (B0), cin, 0,0,0); \
    _Pragma("unroll")                                                               \
    for (int rt = 0; rt < 4; ++rt) acc[rt] = __builtin_amdgcn_mfma_f32_16x16x32_f16(a[rt][1], (B1), acc[rt], 0,0,0); \
    _Pragma("unroll")                                                               \
    for (int rt = 0; rt < 4; ++rt) acc[rt] = __builtin_amdgcn_mfma_f32_16x16x32_f16(a[rt][2], (B0), acc[rt], 0,0,0); \
    _Pragma("unroll")                                                               \
    for (int rt = 0; rt < 4; ++rt) acc[rt] = __builtin_amdgcn_mfma_f32_16x16x32_f16(a[rt][3], (B1), acc[rt], 0,0,0); \
    _Pragma("unroll")                                                               \
    for (int rt = 0; rt < 4; ++rt) acc[rt] = __builtin_amdgcn_mfma_f32_16x16x32_f16(a[rt][0], (B2), acc[rt], 0,0,0); \
    _Pragma("unroll")                                                               \
    for (int rt = 0; rt < 4; ++rt) acc[rt] = __builtin_amdgcn_mfma_f32_16x16x32_f16(a[rt][1], (B3), acc[rt], 0,0,0); \
    const int kk = (I)*64 + cg*16 + n16;                                            \
    _Pragma("unroll")                                                               \
    for (int rt = 0; rt < 4; ++rt)                                                  \
      _Pragma("unroll")                                                             \
      for (int reg = 0; reg < 4; ++reg) {                                           \
        const float dist = acc[rt][reg];                                            \
        const int bi = rt*4 + reg;                                                  \
        if (dist < best[bi]) { best[bi] = dist; bestk[bi] = kk; }                   \
      }                                                                             \
  }

#define LOADB(I, C0, C1, C2, C3, CW)                                                \
  {                                                                                 \
    const size_t base = ((size_t)((I)*4 + cg) * 256) * 8 + lane8;                   \
    C0 = *(const f16x8*)&wfrag[base];                                               \
    C1 = *(const f16x8*)&wfrag[base + 512];                                         \
    C2 = *(const f16x8*)&wfrag[base + 1024];                                        \
    C3 = *(const f16x8*)&wfrag[base + 1536];                                        \
    CW = w2hg[(I)*64 + cg*16 + n16];                                                \
  }

// argmin (r6-exact): 256 blocks x 512 threads (8 waves = rg2 x cg4),
// 128 rows/block, rt=4, B-frags from global frag image, no barriers/LDS in
// K-loop, explicit unroll-2 register double-buffer. EMA atomics fused.
__global__ __launch_bounds__(512) void argmin_kernel(const float* __restrict__ xg,
                                                     float* __restrict__ out,
                                                     float* __restrict__ ws) {
  __shared__ __align__(16) _Float16 xp[8*4*64*8];   // 32 KB, X frags (negated)
  __shared__ float md[128*4];
  __shared__ int   mk[128*4];
  __shared__ int   bkL[128];

  const int t    = threadIdx.x;
  const int lane = t & 63, wv = t >> 6;
  const int quad = lane >> 4, n16 = lane & 15;
  const int rg = wv >> 2, cg = wv & 3;
  const int row0 = blockIdx.x * 128;
  const _Float16* __restrict__ wfrag = (const _Float16*)(ws + WS_WFRAG);
  const float* __restrict__ w2hg = ws + WS_W2H;

  // ---- prologue: convert X tile (NEGATED) into fragment layout ----
#pragma unroll
  for (int it = 0; it < 2; ++it) {
    const int u  = t + 512*it;          // < 1024 granules
    const int rp = u >> 7, n = (u >> 3) & 15, g = u & 7;
    const float* src = xg + (size_t)(row0 + rp*16 + n)*64 + g*8;
    float4 v0 = *(const float4*)src, v1 = *(const float4*)(src + 4);
    float vv[8] = {v0.x,v0.y,v0.z,v0.w,v1.x,v1.y,v1.z,v1.w};
    f16x8 hi, lo;
#pragma unroll
    for (int j = 0; j < 8; ++j) { _Float16 h, l; split_f16(-vv[j], h, l); hi[j]=h; lo[j]=l; }
    const int slot = (g&3)*16 + n, shi = g >> 2;
    *(f16x8*)&xp[(((rp*4) + shi)*64 + slot)*8]     = hi;
    *(f16x8*)&xp[(((rp*4) + 2 + shi)*64 + slot)*8] = lo;
  }
  __syncthreads();

  // A-frags resident: this wave's 64-row half (rg), 64 VGPRs
  f16x8 a[4][4];
#pragma unroll
  for (int rt = 0; rt < 4; ++rt)
#pragma unroll
    for (int s = 0; s < 4; ++s)
      a[rt][s] = *(const f16x8*)&xp[(((rg*4+rt)*4 + s)*64 + lane)*8];

  float best[16]; int bestk[16];
#pragma unroll
  for (int i = 0; i < 16; ++i) { best[i] = INFINITY; bestk[i] = 0; }

  const size_t lane8 = (size_t)lane * 8;
  f16x8 p0, p1, p2, p3, q0, q1, q2, q3;
  float pw, qw;
  LOADB(0, p0, p1, p2, p3, pw);

  for (int it = 0; it < 128; it += 2) {
    LOADB(it+1, q0, q1, q2, q3, qw);
    COMPUTE_PANEL(it, p0, p1, p2, p3, pw);
    if (it + 2 < 128) LOADB(it+2, p0, p1, p2, p3, pw);
    COMPUTE_PANEL(it+1, q0, q1, q2, q3, qw);
  }

  // ---- merge 16 code-lanes per quad (lexicographic (d,k)) ----
#pragma unroll
  for (int bi = 0; bi < 16; ++bi) {
    float bd = best[bi]; int bk = bestk[bi];
#pragma unroll
    for (int m = 1; m < 16; m <<= 1) {
      const float od = __shfl_xor(bd, m, 64);
      const int   ok = __shfl_xor(bk, m, 64);
      if (od < bd || (od == bd && ok < bk)) { bd = od; bk = ok; }
    }
    best[bi] = bd; bestk[bi] = bk;
  }
  if (n16 == 0) {
#pragma unroll
    for (int rt = 0; rt < 4; ++rt)
#pragma unroll
      for (int reg = 0; reg < 4; ++reg) {
        const int row = rg*64 + rt*16 + quad*4 + reg;
        md[row*4 + cg] = best[rt*4+reg];
        mk[row*4 + cg] = bestk[rt*4+reg];
      }
  }
  __syncthreads();

  if (t < 128) {
    const int row = t;
    float bd = md[row*4]; int bk = mk[row*4];
#pragma unroll
    for (int u = 1; u < 4; ++u) {
      const float d2 = md[row*4 + u]; const int k2 = mk[row*4 + u];
      if (d2 < bd || (d2 == bd && k2 < bk)) { bd = d2; bk = k2; }
    }
    out[OUT_IDX + row0 + row] = (float)bk;
    ((int*)ws)[WS_IDX + row0 + row] = bk;
    bkL[row] = bk;
    atomicAdd(&ws[WS_COUNTS + bk], 1.0f);
  }
  __syncthreads();

  // ---- fused EMA segment-sum: 8 waves x 16 rows, lane = dim ----
#pragma unroll 4
  for (int r = 0; r < 16; ++r) {
    const int row = wv*16 + r;
    const int k = bkL[row];
    atomicAdd(&ws[WS_EMB + (size_t)k*64 + lane],
              xg[(size_t)(row0 + row)*64 + lane]);
  }
}

// update: ncc (was stats) + nws + nw; float4; 512 blocks x 256 threads
__global__ __launch_bounds__(256) void update_kernel(const float* __restrict__ ws0,
                                                     const float* __restrict__ cc,
                                                     float* __restrict__ out,
                                                     float* __restrict__ ws) {
  const int e4 = blockIdx.x * 256 + threadIdx.x;  // < 131072 float4s
  const int k = e4 >> 4;
  const float n = ws[WS_N];
  const float cnt = ws[WS_COUNTS + k];
  const float ncc = __fadd_rn(__fmul_rn(DECAYF, cc[k]), __fmul_rn(OMDF, cnt));
  if ((e4 & 15) == 0) out[OUT_NCC + k] = ncc;
  const float smoothed = __fmul_rn(__fadd_rn(ncc, 1e-5f) / __fadd_rn(n, 0.08192f), n);
  float4 w0 = *(const float4*)(ws0 + (size_t)e4*4);
  float4 em = *(const float4*)(ws + WS_EMB + (size_t)e4*4);
  float wv[4] = {w0.x, w0.y, w0.z, w0.w};
  float ev[4] = {em.x, em.y, em.z, em.w};
  float nwsv[4], nwv[4];
#pragma unroll
  for (int i = 0; i < 4; ++i) {
    nwsv[i] = __fadd_rn(__fmul_rn(DECAYF, wv[i]), __fmul_rn(OMDF, ev[i]));
    nwv[i]  = nwsv[i] / smoothed;   // exact division (reference: nws / smoothed)
  }
  float4 onws = {nwsv[0], nwsv[1], nwsv[2], nwsv[3]};
  float4 onw  = {nwv[0],  nwv[1],  nwv[2],  nwv[3]};
  *(float4*)(out + OUT_NWS + (size_t)e4*4) = onws;
  *(float4*)(out + OUT_NW  + (size_t)e4*4) = onw;
}

// quant: per-block loss partials to WS_LOSSP (counts stay intact for final)
__global__ __launch_bounds__(256) void quant_kernel(const float* __restrict__ xg,
                                                    float* __restrict__ out,
                                                    float* __restrict__ ws) {
  const int t = threadIdx.x;
  const int* idxb = (const int*)ws + WS_IDX;
  float v = 0.0f;
#pragma unroll
  for (int j = 0; j < 4; ++j) {
    const int e4 = (j*512 + blockIdx.x)*256 + t;   // float4 index, coalesced
    const int row = e4 >> 4, d = (e4 & 15) * 4;
    const int k = idxb[row];
    const float* nw = out + OUT_NW + (size_t)k*64 + d;
    float2 q0 = *(const float2*)nw, q1 = *(const float2*)(nw + 2);
    float4 x = *(const float4*)(xg + (size_t)e4*4);
    float qv[4] = {q0.x, q0.y, q1.x, q1.y};
    float xv[4] = {x.x, x.y, x.z, x.w};
    float4 o;
    float ov[4];
#pragma unroll
    for (int i = 0; i < 4; ++i) {
      const float df = __fsub_rn(qv[i], xv[i]);
      ov[i] = __fadd_rn(xv[i], df);
      v = fmaf(df, df, v);
    }
    o.x = ov[0]; o.y = ov[1]; o.z = ov[2]; o.w = ov[3];
    *(float4*)(out + OUT_Q + (size_t)e4*4) = o;
  }
#pragma unroll
  for (int off = 32; off > 0; off >>= 1) v += __shfl_down(v, off);
  __shared__ float sm[4];
  const int lane = t & 63, wid = t >> 6;
  if (lane == 0) sm[wid] = v;
  __syncthreads();
  if (t == 0) ws[WS_LOSSP + blockIdx.x] = (sm[0]+sm[1]) + (sm[2]+sm[3]);
}

// final: loss from 512 partials + entropy from counts; 1 block x 256 threads
__global__ __launch_bounds__(256) void final_kernel(float* __restrict__ out,
                                                    const float* __restrict__ ws) {
  const int t = threadIdx.x;
  float lv = ws[WS_LOSSP + t] + ws[WS_LOSSP + 256 + t];
  float ev = 0.0f;
#pragma unroll
  for (int i = 0; i < 32; ++i) {
    const float cnt = ws[WS_COUNTS + i*256 + t];
    const float p = cnt * (1.0f/32768.0f);
    ev += __fmul_rn(p, logf(__fadd_rn(p, 1e-10f)));
  }
#pragma unroll
  for (int off = 32; off > 0; off >>= 1) {
    lv += __shfl_down(lv, off);
    ev += __shfl_down(ev, off);
  }
  __shared__ float s1[4], s2[4];
  const int lane = t & 63, wid = t >> 6;
  if (lane == 0) { s1[wid] = lv; s2[wid] = ev; }
  __syncthreads();
  if (t == 0) {
    out[OUT_LOSS] = __fmul_rn(0.25f, ((s1[0]+s1[1])+(s1[2]+s1[3])) / 2097152.0f);
    out[OUT_PERP] = expf(-((s2[0]+s2[1])+(s2[2]+s2[3])));
  }
}

extern "C" void kernel_launch(void* const* d_in, const int* in_sizes, int n_in,
                              void* d_out, int out_size, void* d_ws, size_t ws_size,
                              hipStream_t stream) {
  (void)in_sizes; (void)n_in; (void)out_size; (void)ws_size;
  const float* x   = (const float*)d_in[0];
  const float* w   = (const float*)d_in[1];
  const float* cc  = (const float*)d_in[2];
  const float* ws0 = (const float*)d_in[3];
  float* out = (float*)d_out;
  float* ws  = (float*)d_ws;

  hipLaunchKernelGGL(prep_kernel,   dim3(288), dim3(256), 0, stream, w, cc, ws);
  hipLaunchKernelGGL(argmin_kernel, dim3(256), dim3(512), 0, stream, x, out, ws);
  hipLaunchKernelGGL(update_kernel, dim3(512), dim3(256), 0, stream, ws0, cc, out, ws);
  hipLaunchKernelGGL(quant_kernel,  dim3(512), dim3(256), 0, stream, x, out, ws);
  hipLaunchKernelGGL(final_kernel,  dim3(1),   dim3(256), 0, stream, out, ws);
}